// Round 2
// baseline (3971.624 us; speedup 1.0000x reference)
//
#include <hip/hip_runtime.h>
#include <stdint.h>

// Neural-ODE RK4: B=131072 points, 2D state, g(y)=tanh(y@W1+b1)@W2+b2, H=256.
// 100 RK4 steps (tf=1.0, h=0.01), then logits = y@Wf+bf, softmax.
// All inputs/outputs are FP32 (reference is jnp.float32).
// Compute-bound on VALU: 1.34e10 hidden-unit evals, each 4 FMA + exp2 + rcp.

#define NH 256
#define WS_W    0            // 5*NH floats: {c*W1[0,j], c*W1[1,j], c*b1[j], -2h*W2[j,0], -2h*W2[j,1]}
#define WS_BASE (5*NH)       // 2 floats: h*(sum(W2[:,k]) + b2[k])
#define WS_WF   (5*NH + 2)   // 4 floats: Wf row-major
#define WS_BF   (5*NH + 6)   // 2 floats: bf
#define WS_N    (5*NH + 8)   // 1 int: n_steps

__device__ __forceinline__ float fexp2(float x) {
#if __has_builtin(__builtin_amdgcn_exp2f)
  return __builtin_amdgcn_exp2f(x);   // raw v_exp_f32
#else
  return exp2f(x);
#endif
}
__device__ __forceinline__ float frcp(float x) {
#if __has_builtin(__builtin_amdgcn_rcpf)
  return __builtin_amdgcn_rcpf(x);    // raw v_rcp_f32
#else
  return 1.0f / x;
#endif
}

// One block, 256 threads: fold scales into weights.
__global__ void prep_kernel(const float* __restrict__ w1,
                            const float* __restrict__ b1,
                            const float* __restrict__ w2,
                            const float* __restrict__ b2,
                            const float* __restrict__ wf,
                            const float* __restrict__ bfv,
                            const int* __restrict__ tptr,
                            float* __restrict__ ws) {
  const float h = 0.01f;
  const float c = 2.88539008177792681f;  // 2*log2(e): tanh(z) = 1 - 2/(exp2(c*z)+1)
  int j = threadIdx.x;
  if (j < NH) {
    ws[WS_W + 5 * j + 0] = c * w1[j];            // W1[0][j]
    ws[WS_W + 5 * j + 1] = c * w1[NH + j];       // W1[1][j]
    ws[WS_W + 5 * j + 2] = c * b1[j];
    ws[WS_W + 5 * j + 3] = -2.0f * h * w2[2 * j];      // W2[j][0]
    ws[WS_W + 5 * j + 4] = -2.0f * h * w2[2 * j + 1];  // W2[j][1]
  }
  if (j == 0) {
    float s0 = 0.f, s1 = 0.f;
    for (int k = 0; k < NH; ++k) { s0 += w2[2 * k]; s1 += w2[2 * k + 1]; }
    ws[WS_BASE + 0] = h * (s0 + b2[0]);   // tanh = 1 - 2u; the "+1" part folds here
    ws[WS_BASE + 1] = h * (s1 + b2[1]);
    ws[WS_WF + 0] = wf[0];  // Wf[0][0]
    ws[WS_WF + 1] = wf[1];  // Wf[0][1]
    ws[WS_WF + 2] = wf[2];  // Wf[1][0]
    ws[WS_WF + 3] = wf[3];  // Wf[1][1]
    ws[WS_BF + 0] = bfv[0];
    ws[WS_BF + 1] = bfv[1];
    // Replicate Python: n,t=0,0.0; while t <= tf: n+=1; t+=0.01 (double accumulation)
    double tf = 0.1 * (double)tptr[0];
    double tt = 0.0; int n = 0;
    while (tt <= tf) { n++; tt += 0.01; }
    ((int*)ws)[WS_N] = n;
  }
}

// gh(y) = h*g(y), with all scales pre-folded into ws.
// tanh(z) = 1 - 2u, u = 1/(exp2(c*z)+1).
__device__ __forceinline__ void gh_eval(const float* __restrict__ ws,
                                        float base0, float base1,
                                        float u0, float u1,
                                        float& o0, float& o1) {
  float acc0 = base0, acc1 = base1;
#pragma unroll 8
  for (int j = 0; j < NH; ++j) {
    const float* p = ws + WS_W + 5 * j;   // uniform address -> s_load via K$
    float a0 = p[0], a1 = p[1], a2 = p[2], a3 = p[3], a4 = p[4];
    float z = fmaf(u0, a0, fmaf(u1, a1, a2));
    float e = fexp2(z);                   // z->+inf: e=inf, r=0, tanh=+1 (exact sat)
    float r = frcp(e + 1.0f);
    acc0 = fmaf(a3, r, acc0);
    acc1 = fmaf(a4, r, acc1);
  }
  o0 = acc0; o1 = acc1;
}

__global__ __launch_bounds__(256) void ode_kernel(const float2* __restrict__ x,
                                                  const float* __restrict__ ws,
                                                  float2* __restrict__ out,
                                                  int npts) {
  int i = blockIdx.x * 256 + threadIdx.x;
  if (i >= npts) return;

  float2 xi = x[i];
  float y0 = xi.x, y1 = xi.y;

  const float base0 = ws[WS_BASE + 0];
  const float base1 = ws[WS_BASE + 1];
  const int n = ((const int*)ws)[WS_N];

  for (int s = 0; s < n; ++s) {
    float k10, k11, k20, k21, k30, k31, k40, k41;
    gh_eval(ws, base0, base1, y0, y1, k10, k11);
    gh_eval(ws, base0, base1, fmaf(0.5f, k10, y0), fmaf(0.5f, k11, y1), k20, k21);
    gh_eval(ws, base0, base1, fmaf(0.5f, k20, y0), fmaf(0.5f, k21, y1), k30, k31);
    gh_eval(ws, base0, base1, y0 + k30, y1 + k31, k40, k41);
    y0 += (k10 + 2.0f * (k20 + k30) + k40) * (1.0f / 6.0f);
    y1 += (k11 + 2.0f * (k21 + k31) + k41) * (1.0f / 6.0f);
  }

  // logits = y @ Wf + bf   (Wf row-major [2,2])
  float wf00 = ws[WS_WF + 0], wf01 = ws[WS_WF + 1];
  float wf10 = ws[WS_WF + 2], wf11 = ws[WS_WF + 3];
  float l0 = fmaf(y0, wf00, fmaf(y1, wf10, ws[WS_BF + 0]));
  float l1 = fmaf(y0, wf01, fmaf(y1, wf11, ws[WS_BF + 1]));

  // softmax over the 2 logits
  float m = fmaxf(l0, l1);
  const float log2e = 1.44269504088896340f;
  float e0 = fexp2((l0 - m) * log2e);
  float e1 = fexp2((l1 - m) * log2e);
  float inv = frcp(e0 + e1);

  out[i]        = make_float2(l0, l1);              // logits [B,2]
  out[npts + i] = make_float2(e0 * inv, e1 * inv);  // probas [B,2]
}

extern "C" void kernel_launch(void* const* d_in, const int* in_sizes, int n_in,
                              void* d_out, int out_size, void* d_ws, size_t ws_size,
                              hipStream_t stream) {
  const float* x   = (const float*)d_in[0];
  const float* w1  = (const float*)d_in[1];
  const float* b1  = (const float*)d_in[2];
  const float* w2  = (const float*)d_in[3];
  const float* b2  = (const float*)d_in[4];
  const float* wf  = (const float*)d_in[5];
  const float* bfv = (const float*)d_in[6];
  const int* tptr  = (const int*)d_in[7];
  float* ws = (float*)d_ws;

  int npts = in_sizes[0] / 2;  // 131072

  prep_kernel<<<1, 256, 0, stream>>>(w1, b1, w2, b2, wf, bfv, tptr, ws);
  ode_kernel<<<(npts + 255) / 256, 256, 0, stream>>>(
      (const float2*)x, ws, (float2*)d_out, npts);
}

// Round 3
// 3209.896 us; speedup vs baseline: 1.2373x; 1.2373x over previous
//
#include <hip/hip_runtime.h>
#include <stdint.h>

// Neural-ODE RK4: B=131072 points, 2D state, g(y)=tanh(y@W1+b1)@W2+b2, H=256.
// 100 RK4 steps, logits=y@Wf+bf, softmax. Pure VALU/transcendental-bound.
// R3: packed-fp32 (v_pk_fma_f32) over j-pairs + explicit phase batching for
// trans-pipe ILP. Grid-limited to 2 waves/SIMD -> spend VGPRs on ILP freely.

#define NH 256
#define NPAIR 128
// ws layout: NPAIR groups of 10 floats (pair-interleaved weights), then tail.
// group m: {cW1[0][2m],cW1[0][2m+1], cW1[1][2m],cW1[1][2m+1], cb1[2m],cb1[2m+1],
//           -2hW2[2m][0],-2hW2[2m+1][0], -2hW2[2m][1],-2hW2[2m+1][1]}
#define WS_TAIL (10*NPAIR)
#define WS_BASE (WS_TAIL + 0)   // 2 floats: h*b2[k]
#define WS_WF   (WS_TAIL + 2)   // 4 floats
#define WS_BF   (WS_TAIL + 6)   // 2 floats
#define WS_N    (WS_TAIL + 8)   // 1 int

typedef __attribute__((ext_vector_type(2))) float f32x2;

__device__ __forceinline__ float fexp2(float x) {
#if __has_builtin(__builtin_amdgcn_exp2f)
  return __builtin_amdgcn_exp2f(x);
#else
  return exp2f(x);
#endif
}
__device__ __forceinline__ float frcp(float x) {
#if __has_builtin(__builtin_amdgcn_rcpf)
  return __builtin_amdgcn_rcpf(x);
#else
  return 1.0f / x;
#endif
}
__device__ __forceinline__ f32x2 pk_fma(f32x2 a, f32x2 b, f32x2 c) {
  return __builtin_elementwise_fma(a, b, c);   // -> v_pk_fma_f32 on gfx950
}

__global__ void prep_kernel(const float* __restrict__ w1,
                            const float* __restrict__ b1,
                            const float* __restrict__ w2,
                            const float* __restrict__ b2,
                            const float* __restrict__ wf,
                            const float* __restrict__ bfv,
                            const int* __restrict__ tptr,
                            float* __restrict__ ws) {
  const float h = 0.01f;
  const float c = 2.88539008177792681f;  // 2*log2(e): tanh(z)=1-2/(exp2(c*z)+1)
  int m = threadIdx.x;                   // pair index
  if (m < NPAIR) {
    int j0 = 2 * m, j1 = 2 * m + 1;
    float* g = ws + 10 * m;
    g[0] = c * w1[j0];        g[1] = c * w1[j1];         // W1[0][j]
    g[2] = c * w1[NH + j0];   g[3] = c * w1[NH + j1];    // W1[1][j]
    g[4] = c * b1[j0];        g[5] = c * b1[j1];
    g[6] = -2.0f * h * w2[2 * j0];      g[7] = -2.0f * h * w2[2 * j1];      // W2[j][0]
    g[8] = -2.0f * h * w2[2 * j0 + 1];  g[9] = -2.0f * h * w2[2 * j1 + 1];  // W2[j][1]
  }
  if (m == 0) {
    // tanh = 1 - 2r; the "+1*W2" part: sum_j h*W2[j][k] folds with -2h*W2*0.5?
    // No: keep full fold as before: base_k = h*(sum_j W2[j][k] + b2[k]).
    float s0 = 0.f, s1 = 0.f;
    for (int k = 0; k < NH; ++k) { s0 += w2[2 * k]; s1 += w2[2 * k + 1]; }
    ws[WS_BASE + 0] = h * (s0 + b2[0]);
    ws[WS_BASE + 1] = h * (s1 + b2[1]);
    ws[WS_WF + 0] = wf[0]; ws[WS_WF + 1] = wf[1];
    ws[WS_WF + 2] = wf[2]; ws[WS_WF + 3] = wf[3];
    ws[WS_BF + 0] = bfv[0]; ws[WS_BF + 1] = bfv[1];
    // Python: n,t=0,0.0; while t <= tf: n+=1; t+=0.01  (float64 accumulation)
    double tf = 0.1 * (double)tptr[0];
    double tt = 0.0; int n = 0;
    while (tt <= tf) { n++; tt += 0.01; }
    ((int*)ws)[WS_N] = n;
  }
}

// gh(y) = h*g(y). Per j-pair (f32x2 lanes = two hidden units):
//   z2 = u0*a0 + u1*a1 + a2 ; r2 = 1/(exp2(z2)+1) ; acc0 += a3*r2 ; acc1 += a4*r2
#define BATCH 4  // pairs per phase batch (8 hidden units)
__device__ __forceinline__ void gh_eval(const float* __restrict__ ws,
                                        float base0, float base1,
                                        float u0, float u1,
                                        float& o0, float& o1) {
  f32x2 u0v = {u0, u0}, u1v = {u1, u1};
  f32x2 acc0 = {base0, 0.0f};
  f32x2 acc1 = {base1, 0.0f};
  for (int b = 0; b < NPAIR / BATCH; ++b) {
    const f32x2* g = (const f32x2*)(ws + 10 * BATCH * b);  // uniform -> s_load
    f32x2 z[BATCH], r[BATCH];
    // phase 1: z for the whole batch (pk_fma stream)
#pragma unroll
    for (int m = 0; m < BATCH; ++m)
      z[m] = pk_fma(u0v, g[5 * m + 0], pk_fma(u1v, g[5 * m + 1], g[5 * m + 2]));
    // phase 2: transcendental stream (independent exp2s, then rcps)
#pragma unroll
    for (int m = 0; m < BATCH; ++m) {
      f32x2 e;
      e.x = fexp2(z[m].x); e.y = fexp2(z[m].y);
      e = e + 1.0f;                       // v_pk_add_f32
      r[m].x = frcp(e.x); r[m].y = frcp(e.y);
    }
    // phase 3: accumulate (pk_fma, SGPR weight operand)
#pragma unroll
    for (int m = 0; m < BATCH; ++m) {
      acc0 = pk_fma(g[5 * m + 3], r[m], acc0);
      acc1 = pk_fma(g[5 * m + 4], r[m], acc1);
    }
  }
  o0 = acc0.x + acc0.y;
  o1 = acc1.x + acc1.y;
}

__global__ __launch_bounds__(256) void ode_kernel(const float2* __restrict__ x,
                                                  const float* __restrict__ ws,
                                                  float2* __restrict__ out,
                                                  int npts) {
  int i = blockIdx.x * 256 + threadIdx.x;
  if (i >= npts) return;

  float2 xi = x[i];
  float y0 = xi.x, y1 = xi.y;

  const float base0 = ws[WS_BASE + 0];
  const float base1 = ws[WS_BASE + 1];
  const int n = ((const int*)ws)[WS_N];

  for (int s = 0; s < n; ++s) {
    float k10, k11, k20, k21, k30, k31, k40, k41;
    gh_eval(ws, base0, base1, y0, y1, k10, k11);
    gh_eval(ws, base0, base1, fmaf(0.5f, k10, y0), fmaf(0.5f, k11, y1), k20, k21);
    gh_eval(ws, base0, base1, fmaf(0.5f, k20, y0), fmaf(0.5f, k21, y1), k30, k31);
    gh_eval(ws, base0, base1, y0 + k30, y1 + k31, k40, k41);
    y0 += (k10 + 2.0f * (k20 + k30) + k40) * (1.0f / 6.0f);
    y1 += (k11 + 2.0f * (k21 + k31) + k41) * (1.0f / 6.0f);
  }

  float wf00 = ws[WS_WF + 0], wf01 = ws[WS_WF + 1];
  float wf10 = ws[WS_WF + 2], wf11 = ws[WS_WF + 3];
  float l0 = fmaf(y0, wf00, fmaf(y1, wf10, ws[WS_BF + 0]));
  float l1 = fmaf(y0, wf01, fmaf(y1, wf11, ws[WS_BF + 1]));

  float m = fmaxf(l0, l1);
  const float log2e = 1.44269504088896340f;
  float e0 = fexp2((l0 - m) * log2e);
  float e1 = fexp2((l1 - m) * log2e);
  float inv = frcp(e0 + e1);

  out[i]        = make_float2(l0, l1);
  out[npts + i] = make_float2(e0 * inv, e1 * inv);
}

extern "C" void kernel_launch(void* const* d_in, const int* in_sizes, int n_in,
                              void* d_out, int out_size, void* d_ws, size_t ws_size,
                              hipStream_t stream) {
  const float* x   = (const float*)d_in[0];
  const float* w1  = (const float*)d_in[1];
  const float* b1  = (const float*)d_in[2];
  const float* w2  = (const float*)d_in[3];
  const float* b2  = (const float*)d_in[4];
  const float* wf  = (const float*)d_in[5];
  const float* bfv = (const float*)d_in[6];
  const int* tptr  = (const int*)d_in[7];
  float* ws = (float*)d_ws;

  int npts = in_sizes[0] / 2;  // 131072

  prep_kernel<<<1, 256, 0, stream>>>(w1, b1, w2, b2, wf, bfv, tptr, ws);
  ode_kernel<<<(npts + 255) / 256, 256, 0, stream>>>(
      (const float2*)x, ws, (float2*)d_out, npts);
}